// Round 3
// baseline (1265.238 us; speedup 1.0000x reference)
//
#include <hip/hip_runtime.h>
#include <hip/hip_bf16.h>

#define N_NODES 25000
#define N_EDGES 200000
#define N_GRAPHS 64
#define HID 128
#define DEPTH 5

typedef _Float16 half8 __attribute__((ext_vector_type(8)));
typedef float f32x4 __attribute__((ext_vector_type(4)));

__device__ inline half8 pack8(float4 a, float4 b) {
    half8 r;
    r[0] = (_Float16)a.x; r[1] = (_Float16)a.y; r[2] = (_Float16)a.z; r[3] = (_Float16)a.w;
    r[4] = (_Float16)b.x; r[5] = (_Float16)b.y; r[6] = (_Float16)b.z; r[7] = (_Float16)b.w;
    return r;
}

// ---------------- embed ----------------
__global__ void embed_kernel(const float* __restrict__ x, const float* __restrict__ W,
                             const float* __restrict__ b, float* __restrict__ h) {
    for (int i = blockIdx.x * blockDim.x + threadIdx.x; i < N_NODES * HID;
         i += gridDim.x * blockDim.x) {
        int n = i >> 7, j = i & 127;
        float acc = b[j];
        #pragma unroll
        for (int k = 0; k < 16; k++) acc += x[n * 16 + k] * W[k * 128 + j];
        h[i] = acc;
    }
}

// ---------------- CSR build ----------------
__global__ void hist_kernel(const int* __restrict__ ei, int* __restrict__ cnt) {
    int e = blockIdx.x * blockDim.x + threadIdx.x;
    if (e < N_EDGES) atomicAdd(&cnt[ei[N_EDGES + e]], 1);
}

__global__ void scan_kernel(const int* __restrict__ cnt, int* __restrict__ rowptr,
                            int* __restrict__ cursor) {
    __shared__ int sdata[256];
    __shared__ int carry;
    if (threadIdx.x == 0) carry = 0;
    __syncthreads();
    for (int base = 0; base < N_NODES; base += 256) {
        int i = base + threadIdx.x;
        int v = (i < N_NODES) ? cnt[i] : 0;
        sdata[threadIdx.x] = v;
        __syncthreads();
        #pragma unroll
        for (int off = 1; off < 256; off <<= 1) {
            int t = (threadIdx.x >= off) ? sdata[threadIdx.x - off] : 0;
            __syncthreads();
            sdata[threadIdx.x] += t;
            __syncthreads();
        }
        int excl = sdata[threadIdx.x] - v + carry;
        if (i < N_NODES) { rowptr[i] = excl; cursor[i] = excl; }
        __syncthreads();
        if (threadIdx.x == 255) carry += sdata[255];
        __syncthreads();
    }
    if (threadIdx.x == 0) rowptr[N_NODES] = carry;
}

__global__ void scatter_kernel(const int* __restrict__ ei, const float* __restrict__ pos,
                               int* __restrict__ cursor, int* __restrict__ src_s,
                               int* __restrict__ dst_s, float* __restrict__ dist_s) {
    int e = blockIdx.x * blockDim.x + threadIdx.x;
    if (e < N_EDGES) {
        int s = ei[e], d = ei[N_EDGES + e];
        int p = atomicAdd(&cursor[d], 1);
        src_s[p] = s; dst_s[p] = d;
        float dx = pos[d * 3 + 0] - pos[s * 3 + 0];
        float dy = pos[d * 3 + 1] - pos[s * 3 + 1];
        float dz = pos[d * 3 + 2] - pos[s * 3 + 2];
        dist_s[p] = sqrtf(dx * dx + dy * dy + dz * dz);
    }
}

// ---------------- US precompute: U = h@W1[0:128]+b1, S = h@W1[128:256] ----------------
__global__ __launch_bounds__(512, 2)
void us_kernel(const float* __restrict__ h, const float* __restrict__ W1,
               const float* __restrict__ bias1,
               _Float16* __restrict__ U, _Float16* __restrict__ S) {
    __shared__ _Float16 sW[32768];   // [kb(4)][tt(16)][lane(64)][j(8)]
    __shared__ float sB1[128];
    const int tid = threadIdx.x;
    for (int idx = tid; idx < 128 * 256; idx += 512) {
        int kk = idx >> 8, c = idx & 255;
        int cc = c & 127, s_ = cc >> 3, tt = (cc & 7) + ((c >> 7) << 3);
        float val = (c < 128) ? W1[kk * 128 + c] : W1[(128 + kk) * 128 + (c - 128)];
        int kb = kk >> 5, kq = (kk >> 3) & 3, j = kk & 7;
        sW[((((kb << 4) + tt) << 6) + ((kq << 4) | s_)) * 8 + j] = (_Float16)val;
    }
    if (tid < 128) sB1[tid] = bias1[tid];
    __syncthreads();

    const int w = tid >> 6, lane = tid & 63, quad = lane >> 4, s = lane & 15;
    float b1c[8];
    #pragma unroll
    for (int t = 0; t < 8; t++) b1c[t] = sB1[s * 8 + t];

    const int ntiles = (N_NODES + 127) >> 7;
    for (int tile = blockIdx.x; tile < ntiles; tile += gridDim.x) {
        const int nbase = (tile << 7) + (w << 4);
        int n = nbase + s; if (n >= N_NODES) n = N_NODES - 1;
        f32x4 acc[16];
        #pragma unroll
        for (int tt = 0; tt < 16; tt++) { f32x4 z = {0.f, 0.f, 0.f, 0.f}; acc[tt] = z; }
        #pragma unroll
        for (int kb = 0; kb < 4; kb++) {
            const float* rp = h + (size_t)n * 128 + kb * 32 + quad * 8;
            half8 af = pack8(*(const float4*)rp, *(const float4*)(rp + 4));
            #pragma unroll
            for (int tt = 0; tt < 16; tt++) {
                half8 bf = *(const half8*)(&sW[((((kb << 4) + tt) << 6) + lane) * 8]);
                acc[tt] = __builtin_amdgcn_mfma_f32_16x16x32_f16(af, bf, acc[tt], 0, 0, 0);
            }
        }
        #pragma unroll
        for (int r = 0; r < 4; r++) {
            int nn = nbase + quad * 4 + r;
            if (nn < N_NODES) {
                half8 uv, sv;
                #pragma unroll
                for (int t = 0; t < 8; t++) {
                    uv[t] = (_Float16)(acc[t][r] + b1c[t]);
                    sv[t] = (_Float16)(acc[t + 8][r]);
                }
                *(half8*)(&U[(size_t)nn * 128 + s * 8]) = uv;
                *(half8*)(&S[(size_t)nn * 128 + s * 8]) = sv;
            }
        }
    }
}

// ---------------- edge kernel: m1 = relu(LN(U[d]+S[s]+dist*w256)); m2 = relu(LN(m1@W2+b2)) ----------------
__global__ __launch_bounds__(256, 2)
void edge_kernel(const _Float16* __restrict__ U, const _Float16* __restrict__ S,
                 const float* __restrict__ dist_s, const int* __restrict__ src_s,
                 const int* __restrict__ dst_s,
                 const float* __restrict__ w256, const float* __restrict__ gam1,
                 const float* __restrict__ bet1,
                 const float* __restrict__ W2, const float* __restrict__ bias2,
                 const float* __restrict__ gam2, const float* __restrict__ bet2,
                 _Float16* __restrict__ m2) {
    __shared__ _Float16 sW2[16384];   // [kb(4)][t(8)][lane(64)][j(8)]
    __shared__ _Float16 sM1[17408];   // per-wave [32 rows][136]
    __shared__ float sB[768];

    const int tid = threadIdx.x;
    for (int idx = tid; idx < 128 * 128; idx += 256) {
        int k = idx >> 7, c = idx & 127;
        int s_ = c >> 3, t = c & 7, kb = k >> 5, kq = (k >> 3) & 3, j = k & 7;
        sW2[((((kb << 3) + t) << 6) + ((kq << 4) | s_)) * 8 + j] = (_Float16)W2[idx];
    }
    if (tid < 128) {
        sB[tid] = w256[tid];
        sB[128 + tid] = gam1[tid]; sB[256 + tid] = bet1[tid];
        sB[384 + tid] = bias2[tid]; sB[512 + tid] = gam2[tid]; sB[640 + tid] = bet2[tid];
    }
    __syncthreads();

    const int w = tid >> 6, lane = tid & 63, quad = lane >> 4, s = lane & 15;
    _Float16* myM1 = &sM1[w * (32 * 136)];

    float w256c[8], g1c[8], be1c[8], b2c[8], g2c[8], be2c[8];
    #pragma unroll
    for (int t = 0; t < 8; t++) {
        int c = s * 8 + t;
        w256c[t] = sB[c]; g1c[t] = sB[128 + c]; be1c[t] = sB[256 + c];
        b2c[t] = sB[384 + c]; g2c[t] = sB[512 + c]; be2c[t] = sB[640 + c];
    }

    const int ntiles = (N_EDGES + 127) >> 7;
    for (int tile = blockIdx.x; tile < ntiles; tile += gridDim.x) {
        const int ebase = (tile << 7) + (w << 5);

        // phase 1: gather + LN + relu -> myM1 (per-wave; no barrier needed)
        #pragma unroll
        for (int mt = 0; mt < 2; mt++) {
            #pragma unroll
            for (int r = 0; r < 4; r++) {
                int e = ebase + mt * 16 + quad * 4 + r;
                int ec = (e >= N_EDGES) ? (N_EDGES - 1) : e;
                int d = dst_s[ec], si = src_s[ec];
                float dist = dist_s[ec];
                half8 u8 = *(const half8*)(&U[(size_t)d * 128 + s * 8]);
                half8 s8 = *(const half8*)(&S[(size_t)si * 128 + s * 8]);
                float v[8], sum = 0.f, sq = 0.f;
                #pragma unroll
                for (int t = 0; t < 8; t++) {
                    v[t] = (float)u8[t] + (float)s8[t] + dist * w256c[t];
                    sum += v[t]; sq += v[t] * v[t];
                }
                #pragma unroll
                for (int m = 1; m < 16; m <<= 1) {
                    sum += __shfl_xor(sum, m, 64);
                    sq  += __shfl_xor(sq, m, 64);
                }
                float mean = sum * (1.f / 128.f);
                float var = sq * (1.f / 128.f) - mean * mean;
                float rstd = rsqrtf(var + 1e-5f);
                half8 hv;
                #pragma unroll
                for (int t = 0; t < 8; t++) {
                    float y = (v[t] - mean) * rstd * g1c[t] + be1c[t];
                    hv[t] = (_Float16)fmaxf(y, 0.f);
                }
                *(half8*)(&myM1[(mt * 16 + quad * 4 + r) * 136 + s * 8]) = hv;
            }
        }

        // GEMM2
        f32x4 acc2[2][8];
        #pragma unroll
        for (int mt = 0; mt < 2; mt++)
            #pragma unroll
            for (int t = 0; t < 8; t++) { f32x4 z = {0.f, 0.f, 0.f, 0.f}; acc2[mt][t] = z; }
        #pragma unroll
        for (int kb = 0; kb < 4; kb++) {
            half8 af[2];
            #pragma unroll
            for (int mt = 0; mt < 2; mt++)
                af[mt] = *(const half8*)(&myM1[(mt * 16 + s) * 136 + kb * 32 + quad * 8]);
            #pragma unroll
            for (int t = 0; t < 8; t++) {
                half8 bf = *(const half8*)(&sW2[(((kb << 3) + t) * 64 + lane) * 8]);
                acc2[0][t] = __builtin_amdgcn_mfma_f32_16x16x32_f16(af[0], bf, acc2[0][t], 0, 0, 0);
                acc2[1][t] = __builtin_amdgcn_mfma_f32_16x16x32_f16(af[1], bf, acc2[1][t], 0, 0, 0);
            }
        }

        // epilogue 2: LN ; relu ; store m2
        #pragma unroll
        for (int mt = 0; mt < 2; mt++) {
            #pragma unroll
            for (int r = 0; r < 4; r++) {
                int e = ebase + mt * 16 + quad * 4 + r;
                float v[8], sum = 0.f, sq = 0.f;
                #pragma unroll
                for (int t = 0; t < 8; t++) {
                    v[t] = acc2[mt][t][r] + b2c[t];
                    sum += v[t]; sq += v[t] * v[t];
                }
                #pragma unroll
                for (int m = 1; m < 16; m <<= 1) {
                    sum += __shfl_xor(sum, m, 64);
                    sq  += __shfl_xor(sq, m, 64);
                }
                float mean = sum * (1.f / 128.f);
                float var = sq * (1.f / 128.f) - mean * mean;
                float rstd = rsqrtf(var + 1e-5f);
                if (e < N_EDGES) {
                    half8 hv;
                    #pragma unroll
                    for (int t = 0; t < 8; t++) {
                        float y = (v[t] - mean) * rstd * g2c[t] + be2c[t];
                        hv[t] = (_Float16)fmaxf(y, 0.f);
                    }
                    *(half8*)(&m2[(size_t)e * 128 + s * 8]) = hv;
                }
            }
        }
    }
}

// ---------------- agg ----------------
__global__ void agg_kernel(const _Float16* __restrict__ m2, const int* __restrict__ rowptr,
                           float* __restrict__ agg) {
    int n = blockIdx.x, j = threadIdx.x;
    int lo = rowptr[n], hi = rowptr[n + 1];
    float s = 0.f;
    for (int r = lo; r < hi; r++) s += (float)m2[(size_t)r * 128 + j];
    agg[(size_t)n * 128 + j] = s;
}

// ---------------- upd (512 thr, 8 waves, M=16/wave) ----------------
__global__ __launch_bounds__(512, 2)
void upd_kernel(float* __restrict__ h, const float* __restrict__ agg,
                const float* __restrict__ W1, const float* __restrict__ bias1,
                const float* __restrict__ gam1, const float* __restrict__ bet1,
                const float* __restrict__ W2, const float* __restrict__ bias2,
                const float* __restrict__ gam2, const float* __restrict__ bet2) {
    __shared__ _Float16 sW1[32768];
    __shared__ _Float16 sW2[16384];
    __shared__ _Float16 sM1[17408];   // 8 waves x [16 rows][136]
    __shared__ float sB[768];

    const int tid = threadIdx.x;
    for (int idx = tid; idx < 256 * 128; idx += 512) {
        int k = idx >> 7, c = idx & 127;
        int s_ = c >> 3, t = c & 7, kb = k >> 5, kq = (k >> 3) & 3, j = k & 7;
        sW1[((((kb << 3) + t) << 6) + ((kq << 4) | s_)) * 8 + j] = (_Float16)W1[idx];
    }
    for (int idx = tid; idx < 128 * 128; idx += 512) {
        int k = idx >> 7, c = idx & 127;
        int s_ = c >> 3, t = c & 7, kb = k >> 5, kq = (k >> 3) & 3, j = k & 7;
        sW2[((((kb << 3) + t) << 6) + ((kq << 4) | s_)) * 8 + j] = (_Float16)W2[idx];
    }
    if (tid < 128) {
        sB[tid] = bias1[tid]; sB[128 + tid] = gam1[tid]; sB[256 + tid] = bet1[tid];
        sB[384 + tid] = bias2[tid]; sB[512 + tid] = gam2[tid]; sB[640 + tid] = bet2[tid];
    }
    __syncthreads();

    const int w = tid >> 6, lane = tid & 63, quad = lane >> 4, s = lane & 15;
    _Float16* myM1 = &sM1[w * (16 * 136)];

    float b1c[8], g1c[8], be1c[8], b2c[8], g2c[8], be2c[8];
    #pragma unroll
    for (int t = 0; t < 8; t++) {
        int c = s * 8 + t;
        b1c[t] = sB[c]; g1c[t] = sB[128 + c]; be1c[t] = sB[256 + c];
        b2c[t] = sB[384 + c]; g2c[t] = sB[512 + c]; be2c[t] = sB[640 + c];
    }

    const int ntiles = (N_NODES + 127) >> 7;
    for (int tile = blockIdx.x; tile < ntiles; tile += gridDim.x) {
        const int nbase = (tile << 7) + (w << 4);
        int n = nbase + s; if (n >= N_NODES) n = N_NODES - 1;

        f32x4 acc[8];
        #pragma unroll
        for (int t = 0; t < 8; t++) { f32x4 z = {0.f, 0.f, 0.f, 0.f}; acc[t] = z; }
        #pragma unroll
        for (int kb = 0; kb < 8; kb++) {
            const float* rp = (kb < 4) ? (h + (size_t)n * 128 + kb * 32 + quad * 8)
                                       : (agg + (size_t)n * 128 + (kb - 4) * 32 + quad * 8);
            half8 af = pack8(*(const float4*)rp, *(const float4*)(rp + 4));
            #pragma unroll
            for (int t = 0; t < 8; t++) {
                half8 bf = *(const half8*)(&sW1[(((kb << 3) + t) * 64 + lane) * 8]);
                acc[t] = __builtin_amdgcn_mfma_f32_16x16x32_f16(af, bf, acc[t], 0, 0, 0);
            }
        }

        #pragma unroll
        for (int r = 0; r < 4; r++) {
            float v[8], sum = 0.f, sq = 0.f;
            #pragma unroll
            for (int t = 0; t < 8; t++) {
                v[t] = acc[t][r] + b1c[t];
                sum += v[t]; sq += v[t] * v[t];
            }
            #pragma unroll
            for (int m = 1; m < 16; m <<= 1) {
                sum += __shfl_xor(sum, m, 64);
                sq  += __shfl_xor(sq, m, 64);
            }
            float mean = sum * (1.f / 128.f);
            float var = sq * (1.f / 128.f) - mean * mean;
            float rstd = rsqrtf(var + 1e-5f);
            half8 hv;
            #pragma unroll
            for (int t = 0; t < 8; t++) {
                float y = (v[t] - mean) * rstd * g1c[t] + be1c[t];
                hv[t] = (_Float16)fmaxf(y, 0.f);
            }
            *(half8*)(&myM1[(quad * 4 + r) * 136 + s * 8]) = hv;
        }

        f32x4 acc2[8];
        #pragma unroll
        for (int t = 0; t < 8; t++) { f32x4 z = {0.f, 0.f, 0.f, 0.f}; acc2[t] = z; }
        #pragma unroll
        for (int kb = 0; kb < 4; kb++) {
            half8 af = *(const half8*)(&myM1[s * 136 + kb * 32 + quad * 8]);
            #pragma unroll
            for (int t = 0; t < 8; t++) {
                half8 bf = *(const half8*)(&sW2[(((kb << 3) + t) * 64 + lane) * 8]);
                acc2[t] = __builtin_amdgcn_mfma_f32_16x16x32_f16(af, bf, acc2[t], 0, 0, 0);
            }
        }

        #pragma unroll
        for (int r = 0; r < 4; r++) {
            int nn = nbase + quad * 4 + r;
            float v[8], sum = 0.f, sq = 0.f;
            #pragma unroll
            for (int t = 0; t < 8; t++) {
                v[t] = acc2[t][r] + b2c[t];
                sum += v[t]; sq += v[t] * v[t];
            }
            #pragma unroll
            for (int m = 1; m < 16; m <<= 1) {
                sum += __shfl_xor(sum, m, 64);
                sq  += __shfl_xor(sq, m, 64);
            }
            float mean = sum * (1.f / 128.f);
            float var = sq * (1.f / 128.f) - mean * mean;
            float rstd = rsqrtf(var + 1e-5f);
            if (nn < N_NODES) {
                float* hp = h + (size_t)nn * 128 + s * 8;
                float4 h0 = *(float4*)hp;
                float4 h1 = *(float4*)(hp + 4);
                float y[8];
                #pragma unroll
                for (int t = 0; t < 8; t++) {
                    float u = (v[t] - mean) * rstd * g2c[t] + be2c[t];
                    y[t] = fmaxf(u, 0.f);
                }
                h0.x += y[0]; h0.y += y[1]; h0.z += y[2]; h0.w += y[3];
                h1.x += y[4]; h1.y += y[5]; h1.z += y[6]; h1.w += y[7];
                *(float4*)hp = h0;
                *(float4*)(hp + 4) = h1;
            }
        }
    }
}

// ---------------- pool / pred ----------------
__device__ inline int lbound(const int* a, int n, int key) {
    int lo = 0, hi = n;
    while (lo < hi) { int mid = (lo + hi) >> 1; if (a[mid] < key) lo = mid + 1; else hi = mid; }
    return lo;
}

__global__ void pool_kernel(const float* __restrict__ h, const int* __restrict__ batch,
                            float* __restrict__ g) {
    int b = blockIdx.x, j = threadIdx.x;
    int lo = lbound(batch, N_NODES, b), hi = lbound(batch, N_NODES, b + 1);
    float sum = 0.f;
    for (int n = lo; n < hi; n++) sum += h[(size_t)n * 128 + j];
    g[b * 128 + j] = sum;
}

__global__ void pred_kernel(const float* __restrict__ g, const float* __restrict__ W1,
                            const float* __restrict__ b1, const float* __restrict__ W2,
                            const float* __restrict__ b2, float* __restrict__ out) {
    int b = blockIdx.x, j = threadIdx.x;
    float t = b1[j];
    for (int k = 0; k < 128; k++) t += g[b * 128 + k] * W1[k * 128 + j];
    t = fmaxf(t, 0.f);
    __shared__ float red[128];
    red[j] = t * W2[j];
    __syncthreads();
    for (int off = 64; off > 0; off >>= 1) {
        if (j < off) red[j] += red[j + off];
        __syncthreads();
    }
    if (j == 0) out[b] = red[0] + b2[0];
}

extern "C" void kernel_launch(void* const* d_in, const int* in_sizes, int n_in,
                              void* d_out, int out_size, void* d_ws, size_t ws_size,
                              hipStream_t stream) {
    const float* x      = (const float*)d_in[0];
    const float* pos    = (const float*)d_in[1];
    const int*   ei     = (const int*)d_in[2];
    const int*   batch  = (const int*)d_in[3];
    const float* emb_W  = (const float*)d_in[4];
    const float* emb_b  = (const float*)d_in[5];
    const float* msg_W1 = (const float*)d_in[6];
    const float* msg_b1 = (const float*)d_in[7];
    const float* msg_W2 = (const float*)d_in[8];
    const float* msg_b2 = (const float*)d_in[9];
    const float* upd_W1 = (const float*)d_in[10];
    const float* upd_b1 = (const float*)d_in[11];
    const float* upd_W2 = (const float*)d_in[12];
    const float* upd_b2 = (const float*)d_in[13];
    const float* msg_g1 = (const float*)d_in[14];
    const float* msg_be1= (const float*)d_in[15];
    const float* msg_g2 = (const float*)d_in[16];
    const float* msg_be2= (const float*)d_in[17];
    const float* upd_g1 = (const float*)d_in[18];
    const float* upd_be1= (const float*)d_in[19];
    const float* upd_g2 = (const float*)d_in[20];
    const float* upd_be2= (const float*)d_in[21];
    const float* pred_W1= (const float*)d_in[22];
    const float* pred_b1= (const float*)d_in[23];
    const float* pred_W2= (const float*)d_in[24];
    const float* pred_b2= (const float*)d_in[25];
    float* out = (float*)d_out;

    float* ws = (float*)d_ws;
    float*     h      = ws;                          // 3.2M floats
    _Float16*  U      = (_Float16*)(ws + 3200000);   // 3.2M f16 (1.6M slots)
    _Float16*  S      = (_Float16*)(ws + 4800000);   // 3.2M f16 (1.6M slots)
    float*     agg    = ws + 3200000;                // aliases U,S (dead when agg written)
    _Float16*  m2     = (_Float16*)(ws + 6400000);   // 25.6M f16 (12.8M slots)
    int*       cnt    = (int*)(ws + 19200000);
    int*       rowptr = cnt + 25008;
    int*       cursor = rowptr + 25008;
    int*       src_s  = cursor + 25008;
    int*       dst_s  = src_s + 200000;
    float*     dist_s = (float*)(dst_s + 200000);
    float*     g      = dist_s + 200000;

    hipMemsetAsync(cnt, 0, 25001 * sizeof(int), stream);
    hist_kernel<<<(N_EDGES + 255) / 256, 256, 0, stream>>>(ei, cnt);
    scan_kernel<<<1, 256, 0, stream>>>(cnt, rowptr, cursor);
    scatter_kernel<<<(N_EDGES + 255) / 256, 256, 0, stream>>>(ei, pos, cursor, src_s, dst_s, dist_s);

    embed_kernel<<<4096, 256, 0, stream>>>(x, emb_W, emb_b, h);

    for (int l = 0; l < DEPTH; l++) {
        const float* W1l = msg_W1 + (size_t)l * 257 * 128;
        us_kernel<<<196, 512, 0, stream>>>(h, W1l, msg_b1 + l * 128, U, S);
        edge_kernel<<<512, 256, 0, stream>>>(
            U, S, dist_s, src_s, dst_s,
            W1l + 256 * 128, msg_g1 + l * 128, msg_be1 + l * 128,
            msg_W2 + (size_t)l * 128 * 128, msg_b2 + l * 128, msg_g2 + l * 128, msg_be2 + l * 128,
            m2);
        agg_kernel<<<N_NODES, 128, 0, stream>>>(m2, rowptr, agg);
        upd_kernel<<<196, 512, 0, stream>>>(
            h, agg,
            upd_W1 + (size_t)l * 256 * 128, upd_b1 + l * 128, upd_g1 + l * 128, upd_be1 + l * 128,
            upd_W2 + (size_t)l * 128 * 128, upd_b2 + l * 128, upd_g2 + l * 128, upd_be2 + l * 128);
    }

    pool_kernel<<<64, 128, 0, stream>>>(h, batch, g);
    pred_kernel<<<64, 128, 0, stream>>>(g, pred_W1, pred_b1, pred_W2, pred_b2, out);
}

// Round 4
// 1215.472 us; speedup vs baseline: 1.0409x; 1.0409x over previous
//
#include <hip/hip_runtime.h>
#include <hip/hip_bf16.h>

#define N_NODES 25000
#define N_EDGES 200000
#define N_GRAPHS 64
#define HID 128
#define DEPTH 5

typedef _Float16 half8 __attribute__((ext_vector_type(8)));
typedef float f32x4 __attribute__((ext_vector_type(4)));

__device__ inline half8 pack8(float4 a, float4 b) {
    half8 r;
    r[0] = (_Float16)a.x; r[1] = (_Float16)a.y; r[2] = (_Float16)a.z; r[3] = (_Float16)a.w;
    r[4] = (_Float16)b.x; r[5] = (_Float16)b.y; r[6] = (_Float16)b.z; r[7] = (_Float16)b.w;
    return r;
}

// ---------------- embed ----------------
__global__ void embed_kernel(const float* __restrict__ x, const float* __restrict__ W,
                             const float* __restrict__ b, float* __restrict__ h) {
    for (int i = blockIdx.x * blockDim.x + threadIdx.x; i < N_NODES * HID;
         i += gridDim.x * blockDim.x) {
        int n = i >> 7, j = i & 127;
        float acc = b[j];
        #pragma unroll
        for (int k = 0; k < 16; k++) acc += x[n * 16 + k] * W[k * 128 + j];
        h[i] = acc;
    }
}

// ---------------- CSR build ----------------
__global__ void hist_kernel(const int* __restrict__ ei, int* __restrict__ cnt) {
    int e = blockIdx.x * blockDim.x + threadIdx.x;
    if (e < N_EDGES) atomicAdd(&cnt[ei[N_EDGES + e]], 1);
}

// 1024-thread wave-shuffle scan: 25 chunks x 3 barriers (was 98 x ~18)
__global__ __launch_bounds__(1024)
void scan_kernel(const int* __restrict__ cnt, int* __restrict__ rowptr,
                 int* __restrict__ cursor) {
    __shared__ int swsum[16];
    __shared__ int stot;
    const int tid = threadIdx.x, wave = tid >> 6, lane = tid & 63;
    int carry = 0;
    for (int base = 0; base < N_NODES; base += 1024) {
        int i = base + tid;
        int v0 = (i < N_NODES) ? cnt[i] : 0;
        int v = v0;
        #pragma unroll
        for (int d = 1; d < 64; d <<= 1) {
            int t = __shfl_up(v, d, 64);
            if (lane >= d) v += t;
        }
        if (lane == 63) swsum[wave] = v;
        __syncthreads();
        if (wave == 0) {
            int sv = (lane < 16) ? swsum[lane] : 0;
            int si = sv;
            #pragma unroll
            for (int d = 1; d < 16; d <<= 1) {
                int t = __shfl_up(si, d, 64);
                if (lane >= d) si += t;
            }
            if (lane < 16) swsum[lane] = si - sv;  // exclusive prefix of wave sums
            if (lane == 15) stot = si;             // chunk total
        }
        __syncthreads();
        int excl = v - v0 + swsum[wave] + carry;
        if (i < N_NODES) { rowptr[i] = excl; cursor[i] = excl; }
        carry += stot;
        __syncthreads();
    }
    if (tid == 0) rowptr[N_NODES] = carry;
}

__global__ void scatter_kernel(const int* __restrict__ ei, const float* __restrict__ pos,
                               int* __restrict__ cursor, int* __restrict__ src_s,
                               int* __restrict__ dst_s, float* __restrict__ dist_s) {
    int e = blockIdx.x * blockDim.x + threadIdx.x;
    if (e < N_EDGES) {
        int s = ei[e], d = ei[N_EDGES + e];
        int p = atomicAdd(&cursor[d], 1);
        src_s[p] = s; dst_s[p] = d;
        float dx = pos[d * 3 + 0] - pos[s * 3 + 0];
        float dy = pos[d * 3 + 1] - pos[s * 3 + 1];
        float dz = pos[d * 3 + 2] - pos[s * 3 + 2];
        dist_s[p] = sqrtf(dx * dx + dy * dy + dz * dz);
    }
}

// ---------------- US precompute: U = h@W1[0:128]+b1, S = h@W1[128:256] ----------------
__global__ __launch_bounds__(512, 2)
void us_kernel(const float* __restrict__ h, const float* __restrict__ W1,
               const float* __restrict__ bias1,
               _Float16* __restrict__ U, _Float16* __restrict__ S) {
    __shared__ _Float16 sW[32768];   // [kb(4)][tt(16)][lane(64)][j(8)]
    __shared__ float sB1[128];
    const int tid = threadIdx.x;
    for (int idx = tid; idx < 128 * 256; idx += 512) {
        int kk = idx >> 8, c = idx & 255;
        int cc = c & 127, s_ = cc >> 3, tt = (cc & 7) + ((c >> 7) << 3);
        float val = (c < 128) ? W1[kk * 128 + c] : W1[(128 + kk) * 128 + (c - 128)];
        int kb = kk >> 5, kq = (kk >> 3) & 3, j = kk & 7;
        sW[((((kb << 4) + tt) << 6) + ((kq << 4) | s_)) * 8 + j] = (_Float16)val;
    }
    if (tid < 128) sB1[tid] = bias1[tid];
    __syncthreads();

    const int w = tid >> 6, lane = tid & 63, quad = lane >> 4, s = lane & 15;
    float b1c[8];
    #pragma unroll
    for (int t = 0; t < 8; t++) b1c[t] = sB1[s * 8 + t];

    const int ntiles = (N_NODES + 127) >> 7;
    for (int tile = blockIdx.x; tile < ntiles; tile += gridDim.x) {
        const int nbase = (tile << 7) + (w << 4);
        int n = nbase + s; if (n >= N_NODES) n = N_NODES - 1;
        f32x4 acc[16];
        #pragma unroll
        for (int tt = 0; tt < 16; tt++) { f32x4 z = {0.f, 0.f, 0.f, 0.f}; acc[tt] = z; }
        #pragma unroll
        for (int kb = 0; kb < 4; kb++) {
            const float* rp = h + (size_t)n * 128 + kb * 32 + quad * 8;
            half8 af = pack8(*(const float4*)rp, *(const float4*)(rp + 4));
            #pragma unroll
            for (int tt = 0; tt < 16; tt++) {
                half8 bf = *(const half8*)(&sW[((((kb << 4) + tt) << 6) + lane) * 8]);
                acc[tt] = __builtin_amdgcn_mfma_f32_16x16x32_f16(af, bf, acc[tt], 0, 0, 0);
            }
        }
        #pragma unroll
        for (int r = 0; r < 4; r++) {
            int nn = nbase + quad * 4 + r;
            if (nn < N_NODES) {
                half8 uv, sv;
                #pragma unroll
                for (int t = 0; t < 8; t++) {
                    uv[t] = (_Float16)(acc[t][r] + b1c[t]);
                    sv[t] = (_Float16)(acc[t + 8][r]);
                }
                *(half8*)(&U[(size_t)nn * 128 + s * 8]) = uv;
                *(half8*)(&S[(size_t)nn * 128 + s * 8]) = sv;
            }
        }
    }
}

// ---------------- edge kernel ----------------
__global__ __launch_bounds__(256, 2)
void edge_kernel(const _Float16* __restrict__ U, const _Float16* __restrict__ S,
                 const float* __restrict__ dist_s, const int* __restrict__ src_s,
                 const int* __restrict__ dst_s,
                 const float* __restrict__ w256, const float* __restrict__ gam1,
                 const float* __restrict__ bet1,
                 const float* __restrict__ W2, const float* __restrict__ bias2,
                 const float* __restrict__ gam2, const float* __restrict__ bet2,
                 _Float16* __restrict__ m2) {
    __shared__ _Float16 sW2[16384];   // [kb(4)][t(8)][lane(64)][j(8)]
    __shared__ _Float16 sM1[17408];   // per-wave [32 rows][136]
    __shared__ float sB[768];

    const int tid = threadIdx.x;
    for (int idx = tid; idx < 128 * 128; idx += 256) {
        int k = idx >> 7, c = idx & 127;
        int s_ = c >> 3, t = c & 7, kb = k >> 5, kq = (k >> 3) & 3, j = k & 7;
        sW2[((((kb << 3) + t) << 6) + ((kq << 4) | s_)) * 8 + j] = (_Float16)W2[idx];
    }
    if (tid < 128) {
        sB[tid] = w256[tid];
        sB[128 + tid] = gam1[tid]; sB[256 + tid] = bet1[tid];
        sB[384 + tid] = bias2[tid]; sB[512 + tid] = gam2[tid]; sB[640 + tid] = bet2[tid];
    }
    __syncthreads();

    const int w = tid >> 6, lane = tid & 63, quad = lane >> 4, s = lane & 15;
    _Float16* myM1 = &sM1[w * (32 * 136)];

    float w256c[8], g1c[8], be1c[8], b2c[8], g2c[8], be2c[8];
    #pragma unroll
    for (int t = 0; t < 8; t++) {
        int c = s * 8 + t;
        w256c[t] = sB[c]; g1c[t] = sB[128 + c]; be1c[t] = sB[256 + c];
        b2c[t] = sB[384 + c]; g2c[t] = sB[512 + c]; be2c[t] = sB[640 + c];
    }

    const int ntiles = (N_EDGES + 127) >> 7;
    for (int tile = blockIdx.x; tile < ntiles; tile += gridDim.x) {
        const int ebase = (tile << 7) + (w << 5);

        // phase 1: gather + LN + relu -> myM1 (per-wave; in-order DS pipe, no barrier)
        #pragma unroll
        for (int mt = 0; mt < 2; mt++) {
            #pragma unroll
            for (int r = 0; r < 4; r++) {
                int e = ebase + mt * 16 + quad * 4 + r;
                int ec = (e >= N_EDGES) ? (N_EDGES - 1) : e;
                int d = dst_s[ec], si = src_s[ec];
                float dist = dist_s[ec];
                half8 u8 = *(const half8*)(&U[(size_t)d * 128 + s * 8]);
                half8 s8 = *(const half8*)(&S[(size_t)si * 128 + s * 8]);
                float v[8], sum = 0.f, sq = 0.f;
                #pragma unroll
                for (int t = 0; t < 8; t++) {
                    v[t] = (float)u8[t] + (float)s8[t] + dist * w256c[t];
                    sum += v[t]; sq += v[t] * v[t];
                }
                #pragma unroll
                for (int m = 1; m < 16; m <<= 1) {
                    sum += __shfl_xor(sum, m, 64);
                    sq  += __shfl_xor(sq, m, 64);
                }
                float mean = sum * (1.f / 128.f);
                float var = sq * (1.f / 128.f) - mean * mean;
                float rstd = rsqrtf(var + 1e-5f);
                half8 hv;
                #pragma unroll
                for (int t = 0; t < 8; t++) {
                    float y = (v[t] - mean) * rstd * g1c[t] + be1c[t];
                    hv[t] = (_Float16)fmaxf(y, 0.f);
                }
                *(half8*)(&myM1[(mt * 16 + quad * 4 + r) * 136 + s * 8]) = hv;
            }
        }

        // GEMM2
        f32x4 acc2[2][8];
        #pragma unroll
        for (int mt = 0; mt < 2; mt++)
            #pragma unroll
            for (int t = 0; t < 8; t++) { f32x4 z = {0.f, 0.f, 0.f, 0.f}; acc2[mt][t] = z; }
        #pragma unroll
        for (int kb = 0; kb < 4; kb++) {
            half8 af[2];
            #pragma unroll
            for (int mt = 0; mt < 2; mt++)
                af[mt] = *(const half8*)(&myM1[(mt * 16 + s) * 136 + kb * 32 + quad * 8]);
            #pragma unroll
            for (int t = 0; t < 8; t++) {
                half8 bf = *(const half8*)(&sW2[(((kb << 3) + t) * 64 + lane) * 8]);
                acc2[0][t] = __builtin_amdgcn_mfma_f32_16x16x32_f16(af[0], bf, acc2[0][t], 0, 0, 0);
                acc2[1][t] = __builtin_amdgcn_mfma_f32_16x16x32_f16(af[1], bf, acc2[1][t], 0, 0, 0);
            }
        }

        // epilogue 2: LN ; relu ; store m2
        #pragma unroll
        for (int mt = 0; mt < 2; mt++) {
            #pragma unroll
            for (int r = 0; r < 4; r++) {
                int e = ebase + mt * 16 + quad * 4 + r;
                float v[8], sum = 0.f, sq = 0.f;
                #pragma unroll
                for (int t = 0; t < 8; t++) {
                    v[t] = acc2[mt][t][r] + b2c[t];
                    sum += v[t]; sq += v[t] * v[t];
                }
                #pragma unroll
                for (int m = 1; m < 16; m <<= 1) {
                    sum += __shfl_xor(sum, m, 64);
                    sq  += __shfl_xor(sq, m, 64);
                }
                float mean = sum * (1.f / 128.f);
                float var = sq * (1.f / 128.f) - mean * mean;
                float rstd = rsqrtf(var + 1e-5f);
                if (e < N_EDGES) {
                    half8 hv;
                    #pragma unroll
                    for (int t = 0; t < 8; t++) {
                        float y = (v[t] - mean) * rstd * g2c[t] + be2c[t];
                        hv[t] = (_Float16)fmaxf(y, 0.f);
                    }
                    *(half8*)(&m2[(size_t)e * 128 + s * 8]) = hv;
                }
            }
        }
    }
}

// ---------------- upd: fused agg(m2 segments) + node-MLP + residual ----------------
__global__ __launch_bounds__(512, 2)
void upd_kernel(float* __restrict__ h, const _Float16* __restrict__ m2,
                const int* __restrict__ rowptr,
                const float* __restrict__ W1, const float* __restrict__ bias1,
                const float* __restrict__ gam1, const float* __restrict__ bet1,
                const float* __restrict__ W2, const float* __restrict__ bias2,
                const float* __restrict__ gam2, const float* __restrict__ bet2) {
    __shared__ _Float16 sW1[32768];
    __shared__ _Float16 sW2[16384];
    __shared__ _Float16 sM1[17408];   // 8 waves x [16 rows][136]
    __shared__ float sB[768];

    const int tid = threadIdx.x;
    for (int idx = tid; idx < 256 * 128; idx += 512) {
        int k = idx >> 7, c = idx & 127;
        int s_ = c >> 3, t = c & 7, kb = k >> 5, kq = (k >> 3) & 3, j = k & 7;
        sW1[((((kb << 3) + t) << 6) + ((kq << 4) | s_)) * 8 + j] = (_Float16)W1[idx];
    }
    for (int idx = tid; idx < 128 * 128; idx += 512) {
        int k = idx >> 7, c = idx & 127;
        int s_ = c >> 3, t = c & 7, kb = k >> 5, kq = (k >> 3) & 3, j = k & 7;
        sW2[((((kb << 3) + t) << 6) + ((kq << 4) | s_)) * 8 + j] = (_Float16)W2[idx];
    }
    if (tid < 128) {
        sB[tid] = bias1[tid]; sB[128 + tid] = gam1[tid]; sB[256 + tid] = bet1[tid];
        sB[384 + tid] = bias2[tid]; sB[512 + tid] = gam2[tid]; sB[640 + tid] = bet2[tid];
    }
    __syncthreads();

    const int w = tid >> 6, lane = tid & 63, quad = lane >> 4, s = lane & 15;
    _Float16* myM1 = &sM1[w * (16 * 136)];

    float b1c[8], g1c[8], be1c[8], b2c[8], g2c[8], be2c[8];
    #pragma unroll
    for (int t = 0; t < 8; t++) {
        int c = s * 8 + t;
        b1c[t] = sB[c]; g1c[t] = sB[128 + c]; be1c[t] = sB[256 + c];
        b2c[t] = sB[384 + c]; g2c[t] = sB[512 + c]; be2c[t] = sB[640 + c];
    }

    const int ntiles = (N_NODES + 127) >> 7;
    for (int tile = blockIdx.x; tile < ntiles; tile += gridDim.x) {
        const int nbase = (tile << 7) + (w << 4);
        int n = nbase + s; if (n >= N_NODES) n = N_NODES - 1;

        // phase 0: agg for node n, cols [quad*32, quad*32+32) from m2 segments -> myM1 (f16)
        {
            int lo = rowptr[n], hi = rowptr[n + 1];
            float a[32];
            #pragma unroll
            for (int j = 0; j < 32; j++) a[j] = 0.f;
            for (int r = lo; r < hi; r++) {
                const half8* mp = (const half8*)(m2 + (size_t)r * 128 + quad * 32);
                #pragma unroll
                for (int c = 0; c < 4; c++) {
                    half8 x = mp[c];
                    #pragma unroll
                    for (int j = 0; j < 8; j++) a[c * 8 + j] += (float)x[j];
                }
            }
            #pragma unroll
            for (int c = 0; c < 4; c++) {
                half8 out;
                #pragma unroll
                for (int j = 0; j < 8; j++) out[j] = (_Float16)a[c * 8 + j];
                *(half8*)(&myM1[s * 136 + quad * 32 + c * 8]) = out;
            }
        }
        // per-wave LDS, in-order DS pipe -> no barrier needed

        // GEMM1: A = [h[n] | agg] (agg from myM1)
        f32x4 acc[8];
        #pragma unroll
        for (int t = 0; t < 8; t++) { f32x4 z = {0.f, 0.f, 0.f, 0.f}; acc[t] = z; }
        #pragma unroll
        for (int kb = 0; kb < 8; kb++) {
            half8 af;
            if (kb < 4) {
                const float* rp = h + (size_t)n * 128 + kb * 32 + quad * 8;
                af = pack8(*(const float4*)rp, *(const float4*)(rp + 4));
            } else {
                af = *(const half8*)(&myM1[s * 136 + (kb - 4) * 32 + quad * 8]);
            }
            #pragma unroll
            for (int t = 0; t < 8; t++) {
                half8 bf = *(const half8*)(&sW1[(((kb << 3) + t) * 64 + lane) * 8]);
                acc[t] = __builtin_amdgcn_mfma_f32_16x16x32_f16(af, bf, acc[t], 0, 0, 0);
            }
        }

        // epilogue 1: LN ; relu ; -> myM1 (overwrites agg; reads all done)
        #pragma unroll
        for (int r = 0; r < 4; r++) {
            float v[8], sum = 0.f, sq = 0.f;
            #pragma unroll
            for (int t = 0; t < 8; t++) {
                v[t] = acc[t][r] + b1c[t];
                sum += v[t]; sq += v[t] * v[t];
            }
            #pragma unroll
            for (int m = 1; m < 16; m <<= 1) {
                sum += __shfl_xor(sum, m, 64);
                sq  += __shfl_xor(sq, m, 64);
            }
            float mean = sum * (1.f / 128.f);
            float var = sq * (1.f / 128.f) - mean * mean;
            float rstd = rsqrtf(var + 1e-5f);
            half8 hv;
            #pragma unroll
            for (int t = 0; t < 8; t++) {
                float y = (v[t] - mean) * rstd * g1c[t] + be1c[t];
                hv[t] = (_Float16)fmaxf(y, 0.f);
            }
            *(half8*)(&myM1[(quad * 4 + r) * 136 + s * 8]) = hv;
        }

        // GEMM2
        f32x4 acc2[8];
        #pragma unroll
        for (int t = 0; t < 8; t++) { f32x4 z = {0.f, 0.f, 0.f, 0.f}; acc2[t] = z; }
        #pragma unroll
        for (int kb = 0; kb < 4; kb++) {
            half8 af = *(const half8*)(&myM1[s * 136 + kb * 32 + quad * 8]);
            #pragma unroll
            for (int t = 0; t < 8; t++) {
                half8 bf = *(const half8*)(&sW2[(((kb << 3) + t) * 64 + lane) * 8]);
                acc2[t] = __builtin_amdgcn_mfma_f32_16x16x32_f16(af, bf, acc2[t], 0, 0, 0);
            }
        }

        // epilogue 2: LN ; relu ; h += u
        #pragma unroll
        for (int r = 0; r < 4; r++) {
            int nn = nbase + quad * 4 + r;
            float v[8], sum = 0.f, sq = 0.f;
            #pragma unroll
            for (int t = 0; t < 8; t++) {
                v[t] = acc2[t][r] + b2c[t];
                sum += v[t]; sq += v[t] * v[t];
            }
            #pragma unroll
            for (int m = 1; m < 16; m <<= 1) {
                sum += __shfl_xor(sum, m, 64);
                sq  += __shfl_xor(sq, m, 64);
            }
            float mean = sum * (1.f / 128.f);
            float var = sq * (1.f / 128.f) - mean * mean;
            float rstd = rsqrtf(var + 1e-5f);
            if (nn < N_NODES) {
                float* hp = h + (size_t)nn * 128 + s * 8;
                float4 h0 = *(float4*)hp;
                float4 h1 = *(float4*)(hp + 4);
                float y[8];
                #pragma unroll
                for (int t = 0; t < 8; t++) {
                    float u = (v[t] - mean) * rstd * g2c[t] + be2c[t];
                    y[t] = fmaxf(u, 0.f);
                }
                h0.x += y[0]; h0.y += y[1]; h0.z += y[2]; h0.w += y[3];
                h1.x += y[4]; h1.y += y[5]; h1.z += y[6]; h1.w += y[7];
                *(float4*)hp = h0;
                *(float4*)(hp + 4) = h1;
            }
        }
    }
}

// ---------------- pool / pred ----------------
__device__ inline int lbound(const int* a, int n, int key) {
    int lo = 0, hi = n;
    while (lo < hi) { int mid = (lo + hi) >> 1; if (a[mid] < key) lo = mid + 1; else hi = mid; }
    return lo;
}

__global__ void pool_kernel(const float* __restrict__ h, const int* __restrict__ batch,
                            float* __restrict__ g) {
    int b = blockIdx.x, j = threadIdx.x;
    int lo = lbound(batch, N_NODES, b), hi = lbound(batch, N_NODES, b + 1);
    float sum = 0.f;
    for (int n = lo; n < hi; n++) sum += h[(size_t)n * 128 + j];
    g[b * 128 + j] = sum;
}

__global__ void pred_kernel(const float* __restrict__ g, const float* __restrict__ W1,
                            const float* __restrict__ b1, const float* __restrict__ W2,
                            const float* __restrict__ b2, float* __restrict__ out) {
    int b = blockIdx.x, j = threadIdx.x;
    float t = b1[j];
    for (int k = 0; k < 128; k++) t += g[b * 128 + k] * W1[k * 128 + j];
    t = fmaxf(t, 0.f);
    __shared__ float red[128];
    red[j] = t * W2[j];
    __syncthreads();
    for (int off = 64; off > 0; off >>= 1) {
        if (j < off) red[j] += red[j + off];
        __syncthreads();
    }
    if (j == 0) out[b] = red[0] + b2[0];
}

extern "C" void kernel_launch(void* const* d_in, const int* in_sizes, int n_in,
                              void* d_out, int out_size, void* d_ws, size_t ws_size,
                              hipStream_t stream) {
    const float* x      = (const float*)d_in[0];
    const float* pos    = (const float*)d_in[1];
    const int*   ei     = (const int*)d_in[2];
    const int*   batch  = (const int*)d_in[3];
    const float* emb_W  = (const float*)d_in[4];
    const float* emb_b  = (const float*)d_in[5];
    const float* msg_W1 = (const float*)d_in[6];
    const float* msg_b1 = (const float*)d_in[7];
    const float* msg_W2 = (const float*)d_in[8];
    const float* msg_b2 = (const float*)d_in[9];
    const float* upd_W1 = (const float*)d_in[10];
    const float* upd_b1 = (const float*)d_in[11];
    const float* upd_W2 = (const float*)d_in[12];
    const float* upd_b2 = (const float*)d_in[13];
    const float* msg_g1 = (const float*)d_in[14];
    const float* msg_be1= (const float*)d_in[15];
    const float* msg_g2 = (const float*)d_in[16];
    const float* msg_be2= (const float*)d_in[17];
    const float* upd_g1 = (const float*)d_in[18];
    const float* upd_be1= (const float*)d_in[19];
    const float* upd_g2 = (const float*)d_in[20];
    const float* upd_be2= (const float*)d_in[21];
    const float* pred_W1= (const float*)d_in[22];
    const float* pred_b1= (const float*)d_in[23];
    const float* pred_W2= (const float*)d_in[24];
    const float* pred_b2= (const float*)d_in[25];
    float* out = (float*)d_out;

    float* ws = (float*)d_ws;
    float*     h      = ws;                          // 3.2M floats
    _Float16*  U      = (_Float16*)(ws + 3200000);   // 3.2M f16
    _Float16*  S      = (_Float16*)(ws + 4800000);   // 3.2M f16
    _Float16*  m2     = (_Float16*)(ws + 6400000);   // 25.6M f16
    int*       cnt    = (int*)(ws + 19200000);
    int*       rowptr = cnt + 25008;
    int*       cursor = rowptr + 25008;
    int*       src_s  = cursor + 25008;
    int*       dst_s  = src_s + 200000;
    float*     dist_s = (float*)(dst_s + 200000);
    float*     g      = dist_s + 200000;

    hipMemsetAsync(cnt, 0, 25001 * sizeof(int), stream);
    hist_kernel<<<(N_EDGES + 255) / 256, 256, 0, stream>>>(ei, cnt);
    scan_kernel<<<1, 1024, 0, stream>>>(cnt, rowptr, cursor);
    scatter_kernel<<<(N_EDGES + 255) / 256, 256, 0, stream>>>(ei, pos, cursor, src_s, dst_s, dist_s);

    embed_kernel<<<4096, 256, 0, stream>>>(x, emb_W, emb_b, h);

    for (int l = 0; l < DEPTH; l++) {
        const float* W1l = msg_W1 + (size_t)l * 257 * 128;
        us_kernel<<<196, 512, 0, stream>>>(h, W1l, msg_b1 + l * 128, U, S);
        edge_kernel<<<512, 256, 0, stream>>>(
            U, S, dist_s, src_s, dst_s,
            W1l + 256 * 128, msg_g1 + l * 128, msg_be1 + l * 128,
            msg_W2 + (size_t)l * 128 * 128, msg_b2 + l * 128, msg_g2 + l * 128, msg_be2 + l * 128,
            m2);
        upd_kernel<<<196, 512, 0, stream>>>(
            h, m2, rowptr,
            upd_W1 + (size_t)l * 256 * 128, upd_b1 + l * 128, upd_g1 + l * 128, upd_be1 + l * 128,
            upd_W2 + (size_t)l * 128 * 128, upd_b2 + l * 128, upd_g2 + l * 128, upd_be2 + l * 128);
    }

    pool_kernel<<<64, 128, 0, stream>>>(h, batch, g);
    pred_kernel<<<64, 128, 0, stream>>>(g, pred_W1, pred_b1, pred_W2, pred_b2, out);
}

// Round 5
// 1130.406 us; speedup vs baseline: 1.1193x; 1.0753x over previous
//
#include <hip/hip_runtime.h>
#include <hip/hip_bf16.h>

#define N_NODES 25000
#define N_EDGES 200000
#define N_GRAPHS 64
#define HID 128
#define DEPTH 5

typedef _Float16 half8 __attribute__((ext_vector_type(8)));
typedef float f32x4 __attribute__((ext_vector_type(4)));

__device__ inline half8 pack8(float4 a, float4 b) {
    half8 r;
    r[0] = (_Float16)a.x; r[1] = (_Float16)a.y; r[2] = (_Float16)a.z; r[3] = (_Float16)a.w;
    r[4] = (_Float16)b.x; r[5] = (_Float16)b.y; r[6] = (_Float16)b.z; r[7] = (_Float16)b.w;
    return r;
}

// ---------------- embed ----------------
__global__ void embed_kernel(const float* __restrict__ x, const float* __restrict__ W,
                             const float* __restrict__ b, float* __restrict__ h) {
    for (int i = blockIdx.x * blockDim.x + threadIdx.x; i < N_NODES * HID;
         i += gridDim.x * blockDim.x) {
        int n = i >> 7, j = i & 127;
        float acc = b[j];
        #pragma unroll
        for (int k = 0; k < 16; k++) acc += x[n * 16 + k] * W[k * 128 + j];
        h[i] = acc;
    }
}

// ---------------- CSR build ----------------
__global__ void hist_kernel(const int* __restrict__ ei, int* __restrict__ cnt) {
    int e = blockIdx.x * blockDim.x + threadIdx.x;
    if (e < N_EDGES) atomicAdd(&cnt[ei[N_EDGES + e]], 1);
}

__global__ __launch_bounds__(1024)
void scan_kernel(const int* __restrict__ cnt, int* __restrict__ rowptr,
                 int* __restrict__ cursor) {
    __shared__ int swsum[16];
    __shared__ int stot;
    const int tid = threadIdx.x, wave = tid >> 6, lane = tid & 63;
    int carry = 0;
    for (int base = 0; base < N_NODES; base += 1024) {
        int i = base + tid;
        int v0 = (i < N_NODES) ? cnt[i] : 0;
        int v = v0;
        #pragma unroll
        for (int d = 1; d < 64; d <<= 1) {
            int t = __shfl_up(v, d, 64);
            if (lane >= d) v += t;
        }
        if (lane == 63) swsum[wave] = v;
        __syncthreads();
        if (wave == 0) {
            int sv = (lane < 16) ? swsum[lane] : 0;
            int si = sv;
            #pragma unroll
            for (int d = 1; d < 16; d <<= 1) {
                int t = __shfl_up(si, d, 64);
                if (lane >= d) si += t;
            }
            if (lane < 16) swsum[lane] = si - sv;
            if (lane == 15) stot = si;
        }
        __syncthreads();
        int excl = v - v0 + swsum[wave] + carry;
        if (i < N_NODES) { rowptr[i] = excl; cursor[i] = excl; }
        carry += stot;
        __syncthreads();
    }
    if (tid == 0) rowptr[N_NODES] = carry;
}

__global__ void scatter_kernel(const int* __restrict__ ei, const float* __restrict__ pos,
                               int* __restrict__ cursor, int* __restrict__ src_s,
                               int* __restrict__ dst_s, float* __restrict__ dist_s) {
    int e = blockIdx.x * blockDim.x + threadIdx.x;
    if (e < N_EDGES) {
        int s = ei[e], d = ei[N_EDGES + e];
        int p = atomicAdd(&cursor[d], 1);
        src_s[p] = s; dst_s[p] = d;
        float dx = pos[d * 3 + 0] - pos[s * 3 + 0];
        float dy = pos[d * 3 + 1] - pos[s * 3 + 1];
        float dz = pos[d * 3 + 2] - pos[s * 3 + 2];
        dist_s[p] = sqrtf(dx * dx + dy * dy + dz * dz);
    }
}

// ---------------- US precompute ----------------
__global__ __launch_bounds__(512, 2)
void us_kernel(const float* __restrict__ h, const float* __restrict__ W1,
               const float* __restrict__ bias1,
               _Float16* __restrict__ U, _Float16* __restrict__ S) {
    __shared__ _Float16 sW[32768];   // [kb(4)][tt(16)][lane(64)][j(8)]
    __shared__ float sB1[128];
    const int tid = threadIdx.x;
    for (int idx = tid; idx < 128 * 256; idx += 512) {
        int kk = idx >> 8, c = idx & 255;
        int cc = c & 127, s_ = cc >> 3, tt = (cc & 7) + ((c >> 7) << 3);
        float val = (c < 128) ? W1[kk * 128 + c] : W1[(128 + kk) * 128 + (c - 128)];
        int kb = kk >> 5, kq = (kk >> 3) & 3, j = kk & 7;
        sW[((((kb << 4) + tt) << 6) + ((kq << 4) | s_)) * 8 + j] = (_Float16)val;
    }
    if (tid < 128) sB1[tid] = bias1[tid];
    __syncthreads();

    const int w = tid >> 6, lane = tid & 63, quad = lane >> 4, s = lane & 15;
    float b1c[8];
    #pragma unroll
    for (int t = 0; t < 8; t++) b1c[t] = sB1[s * 8 + t];

    const int gw = blockIdx.x * 8 + w, nwaves = gridDim.x * 8;
    const int nwt = (N_NODES + 15) >> 4;   // 16-node wave tiles
    for (int wt = gw; wt < nwt; wt += nwaves) {
        const int nbase = wt << 4;
        int n = nbase + s; if (n >= N_NODES) n = N_NODES - 1;
        f32x4 acc[16];
        #pragma unroll
        for (int tt = 0; tt < 16; tt++) { f32x4 z = {0.f, 0.f, 0.f, 0.f}; acc[tt] = z; }
        #pragma unroll
        for (int kb = 0; kb < 4; kb++) {
            const float* rp = h + (size_t)n * 128 + kb * 32 + quad * 8;
            half8 af = pack8(*(const float4*)rp, *(const float4*)(rp + 4));
            #pragma unroll
            for (int tt = 0; tt < 16; tt++) {
                half8 bf = *(const half8*)(&sW[((((kb << 4) + tt) << 6) + lane) * 8]);
                acc[tt] = __builtin_amdgcn_mfma_f32_16x16x32_f16(af, bf, acc[tt], 0, 0, 0);
            }
        }
        #pragma unroll
        for (int r = 0; r < 4; r++) {
            int nn = nbase + quad * 4 + r;
            if (nn < N_NODES) {
                half8 uv, sv;
                #pragma unroll
                for (int t = 0; t < 8; t++) {
                    uv[t] = (_Float16)(acc[t][r] + b1c[t]);
                    sv[t] = (_Float16)(acc[t + 8][r]);
                }
                *(half8*)(&U[(size_t)nn * 128 + s * 8]) = uv;
                *(half8*)(&S[(size_t)nn * 128 + s * 8]) = sv;
            }
        }
    }
}

// ---------------- edge kernel ----------------
__global__ __launch_bounds__(256, 2)
void edge_kernel(const _Float16* __restrict__ U, const _Float16* __restrict__ S,
                 const float* __restrict__ dist_s, const int* __restrict__ src_s,
                 const int* __restrict__ dst_s,
                 const float* __restrict__ w256, const float* __restrict__ gam1,
                 const float* __restrict__ bet1,
                 const float* __restrict__ W2, const float* __restrict__ bias2,
                 const float* __restrict__ gam2, const float* __restrict__ bet2,
                 _Float16* __restrict__ m2) {
    __shared__ _Float16 sW2[16384];   // [kb(4)][t(8)][lane(64)][j(8)]
    __shared__ _Float16 sM1[17408];   // 4 waves x [32 rows][136]
    __shared__ float sB[768];

    const int tid = threadIdx.x;
    for (int idx = tid; idx < 128 * 128; idx += 256) {
        int k = idx >> 7, c = idx & 127;
        int s_ = c >> 3, t = c & 7, kb = k >> 5, kq = (k >> 3) & 3, j = k & 7;
        sW2[((((kb << 3) + t) << 6) + ((kq << 4) | s_)) * 8 + j] = (_Float16)W2[idx];
    }
    if (tid < 128) {
        sB[tid] = w256[tid];
        sB[128 + tid] = gam1[tid]; sB[256 + tid] = bet1[tid];
        sB[384 + tid] = bias2[tid]; sB[512 + tid] = gam2[tid]; sB[640 + tid] = bet2[tid];
    }
    __syncthreads();

    const int w = tid >> 6, lane = tid & 63, quad = lane >> 4, s = lane & 15;
    _Float16* myM1 = &sM1[w * (32 * 136)];

    float w256c[8], g1c[8], be1c[8], b2c[8], g2c[8], be2c[8];
    #pragma unroll
    for (int t = 0; t < 8; t++) {
        int c = s * 8 + t;
        w256c[t] = sB[c]; g1c[t] = sB[128 + c]; be1c[t] = sB[256 + c];
        b2c[t] = sB[384 + c]; g2c[t] = sB[512 + c]; be2c[t] = sB[640 + c];
    }

    const int gw = blockIdx.x * 4 + w, nwaves = gridDim.x * 4;
    const int ewt = (N_EDGES + 31) >> 5;   // 32-edge wave tiles
    for (int wt = gw; wt < ewt; wt += nwaves) {
        const int ebase = wt << 5;

        // phase A: gather everything (max outstanding loads)
        float distA[8];
        half8 u8A[8], s8A[8];
        int dA[8], siA[8];
        #pragma unroll
        for (int i = 0; i < 8; i++) {
            int e = ebase + (i >> 2) * 16 + quad * 4 + (i & 3);
            int ec = (e >= N_EDGES) ? (N_EDGES - 1) : e;
            dA[i] = dst_s[ec]; siA[i] = src_s[ec]; distA[i] = dist_s[ec];
        }
        #pragma unroll
        for (int i = 0; i < 8; i++) {
            u8A[i] = *(const half8*)(&U[(size_t)dA[i] * 128 + s * 8]);
            s8A[i] = *(const half8*)(&S[(size_t)siA[i] * 128 + s * 8]);
        }

        // phase B: LN + relu -> myM1 (per-wave; in-order DS pipe, no barrier)
        #pragma unroll
        for (int i = 0; i < 8; i++) {
            float v[8], sum = 0.f, sq = 0.f;
            #pragma unroll
            for (int t = 0; t < 8; t++) {
                v[t] = (float)u8A[i][t] + (float)s8A[i][t] + distA[i] * w256c[t];
                sum += v[t]; sq += v[t] * v[t];
            }
            #pragma unroll
            for (int m = 1; m < 16; m <<= 1) {
                sum += __shfl_xor(sum, m, 64);
                sq  += __shfl_xor(sq, m, 64);
            }
            float mean = sum * (1.f / 128.f);
            float var = sq * (1.f / 128.f) - mean * mean;
            float rstd = rsqrtf(var + 1e-5f);
            half8 hv;
            #pragma unroll
            for (int t = 0; t < 8; t++) {
                float y = (v[t] - mean) * rstd * g1c[t] + be1c[t];
                hv[t] = (_Float16)fmaxf(y, 0.f);
            }
            *(half8*)(&myM1[((i >> 2) * 16 + quad * 4 + (i & 3)) * 136 + s * 8]) = hv;
        }

        // GEMM2
        f32x4 acc2[2][8];
        #pragma unroll
        for (int mt = 0; mt < 2; mt++)
            #pragma unroll
            for (int t = 0; t < 8; t++) { f32x4 z = {0.f, 0.f, 0.f, 0.f}; acc2[mt][t] = z; }
        #pragma unroll
        for (int kb = 0; kb < 4; kb++) {
            half8 af[2];
            #pragma unroll
            for (int mt = 0; mt < 2; mt++)
                af[mt] = *(const half8*)(&myM1[(mt * 16 + s) * 136 + kb * 32 + quad * 8]);
            #pragma unroll
            for (int t = 0; t < 8; t++) {
                half8 bf = *(const half8*)(&sW2[(((kb << 3) + t) * 64 + lane) * 8]);
                acc2[0][t] = __builtin_amdgcn_mfma_f32_16x16x32_f16(af[0], bf, acc2[0][t], 0, 0, 0);
                acc2[1][t] = __builtin_amdgcn_mfma_f32_16x16x32_f16(af[1], bf, acc2[1][t], 0, 0, 0);
            }
        }

        // epilogue 2: LN ; relu ; store m2
        #pragma unroll
        for (int mt = 0; mt < 2; mt++) {
            #pragma unroll
            for (int r = 0; r < 4; r++) {
                int e = ebase + mt * 16 + quad * 4 + r;
                float v[8], sum = 0.f, sq = 0.f;
                #pragma unroll
                for (int t = 0; t < 8; t++) {
                    v[t] = acc2[mt][t][r] + b2c[t];
                    sum += v[t]; sq += v[t] * v[t];
                }
                #pragma unroll
                for (int m = 1; m < 16; m <<= 1) {
                    sum += __shfl_xor(sum, m, 64);
                    sq  += __shfl_xor(sq, m, 64);
                }
                float mean = sum * (1.f / 128.f);
                float var = sq * (1.f / 128.f) - mean * mean;
                float rstd = rsqrtf(var + 1e-5f);
                if (e < N_EDGES) {
                    half8 hv;
                    #pragma unroll
                    for (int t = 0; t < 8; t++) {
                        float y = (v[t] - mean) * rstd * g2c[t] + be2c[t];
                        hv[t] = (_Float16)fmaxf(y, 0.f);
                    }
                    *(half8*)(&m2[(size_t)e * 128 + s * 8]) = hv;
                }
            }
        }
    }
}

// ---------------- upd: fused agg + node-MLP + residual ----------------
__global__ __launch_bounds__(512, 2)
void upd_kernel(float* __restrict__ h, const _Float16* __restrict__ m2,
                const int* __restrict__ rowptr,
                const float* __restrict__ W1, const float* __restrict__ bias1,
                const float* __restrict__ gam1, const float* __restrict__ bet1,
                const float* __restrict__ W2, const float* __restrict__ bias2,
                const float* __restrict__ gam2, const float* __restrict__ bet2) {
    __shared__ _Float16 sW1[32768];
    __shared__ _Float16 sW2[16384];
    __shared__ _Float16 sM1[17408];   // 8 waves x [16 rows][136]
    __shared__ float sB[768];

    const int tid = threadIdx.x;
    for (int idx = tid; idx < 256 * 128; idx += 512) {
        int k = idx >> 7, c = idx & 127;
        int s_ = c >> 3, t = c & 7, kb = k >> 5, kq = (k >> 3) & 3, j = k & 7;
        sW1[((((kb << 3) + t) << 6) + ((kq << 4) | s_)) * 8 + j] = (_Float16)W1[idx];
    }
    for (int idx = tid; idx < 128 * 128; idx += 512) {
        int k = idx >> 7, c = idx & 127;
        int s_ = c >> 3, t = c & 7, kb = k >> 5, kq = (k >> 3) & 3, j = k & 7;
        sW2[((((kb << 3) + t) << 6) + ((kq << 4) | s_)) * 8 + j] = (_Float16)W2[idx];
    }
    if (tid < 128) {
        sB[tid] = bias1[tid]; sB[128 + tid] = gam1[tid]; sB[256 + tid] = bet1[tid];
        sB[384 + tid] = bias2[tid]; sB[512 + tid] = gam2[tid]; sB[640 + tid] = bet2[tid];
    }
    __syncthreads();

    const int w = tid >> 6, lane = tid & 63, quad = lane >> 4, s = lane & 15;
    _Float16* myM1 = &sM1[w * (16 * 136)];

    float b1c[8], g1c[8], be1c[8], b2c[8], g2c[8], be2c[8];
    #pragma unroll
    for (int t = 0; t < 8; t++) {
        int c = s * 8 + t;
        b1c[t] = sB[c]; g1c[t] = sB[128 + c]; be1c[t] = sB[256 + c];
        b2c[t] = sB[384 + c]; g2c[t] = sB[512 + c]; be2c[t] = sB[640 + c];
    }

    const int gw = blockIdx.x * 8 + w, nwaves = gridDim.x * 8;
    const int nwt = (N_NODES + 15) >> 4;
    for (int wt = gw; wt < nwt; wt += nwaves) {
        const int nbase = wt << 4;
        int n = nbase + s; if (n >= N_NODES) n = N_NODES - 1;

        // phase 0: agg (f16 packed accumulate, unroll-2) -> myM1
        {
            int lo = rowptr[n], hi = rowptr[n + 1];
            half8 a[4];
            #pragma unroll
            for (int c = 0; c < 4; c++)
                #pragma unroll
                for (int j = 0; j < 8; j++) a[c][j] = (_Float16)0.f;
            int r = lo;
            for (; r + 2 <= hi; r += 2) {
                const half8* p0 = (const half8*)(m2 + (size_t)r * 128 + quad * 32);
                const half8* p1 = (const half8*)(m2 + (size_t)(r + 1) * 128 + quad * 32);
                half8 x0 = p0[0], x1 = p0[1], x2 = p0[2], x3 = p0[3];
                half8 y0 = p1[0], y1 = p1[1], y2 = p1[2], y3 = p1[3];
                a[0] += x0 + y0; a[1] += x1 + y1; a[2] += x2 + y2; a[3] += x3 + y3;
            }
            if (r < hi) {
                const half8* p0 = (const half8*)(m2 + (size_t)r * 128 + quad * 32);
                a[0] += p0[0]; a[1] += p0[1]; a[2] += p0[2]; a[3] += p0[3];
            }
            #pragma unroll
            for (int c = 0; c < 4; c++)
                *(half8*)(&myM1[s * 136 + quad * 32 + c * 8]) = a[c];
        }
        // per-wave LDS, in-order DS pipe -> no barrier needed

        // GEMM1: A = [h[n] | agg]
        f32x4 acc[8];
        #pragma unroll
        for (int t = 0; t < 8; t++) { f32x4 z = {0.f, 0.f, 0.f, 0.f}; acc[t] = z; }
        #pragma unroll
        for (int kb = 0; kb < 8; kb++) {
            half8 af;
            if (kb < 4) {
                const float* rp = h + (size_t)n * 128 + kb * 32 + quad * 8;
                af = pack8(*(const float4*)rp, *(const float4*)(rp + 4));
            } else {
                af = *(const half8*)(&myM1[s * 136 + (kb - 4) * 32 + quad * 8]);
            }
            #pragma unroll
            for (int t = 0; t < 8; t++) {
                half8 bf = *(const half8*)(&sW1[(((kb << 3) + t) * 64 + lane) * 8]);
                acc[t] = __builtin_amdgcn_mfma_f32_16x16x32_f16(af, bf, acc[t], 0, 0, 0);
            }
        }

        // epilogue 1: LN ; relu ; -> myM1
        #pragma unroll
        for (int r = 0; r < 4; r++) {
            float v[8], sum = 0.f, sq = 0.f;
            #pragma unroll
            for (int t = 0; t < 8; t++) {
                v[t] = acc[t][r] + b1c[t];
                sum += v[t]; sq += v[t] * v[t];
            }
            #pragma unroll
            for (int m = 1; m < 16; m <<= 1) {
                sum += __shfl_xor(sum, m, 64);
                sq  += __shfl_xor(sq, m, 64);
            }
            float mean = sum * (1.f / 128.f);
            float var = sq * (1.f / 128.f) - mean * mean;
            float rstd = rsqrtf(var + 1e-5f);
            half8 hv;
            #pragma unroll
            for (int t = 0; t < 8; t++) {
                float y = (v[t] - mean) * rstd * g1c[t] + be1c[t];
                hv[t] = (_Float16)fmaxf(y, 0.f);
            }
            *(half8*)(&myM1[(quad * 4 + r) * 136 + s * 8]) = hv;
        }

        // GEMM2
        f32x4 acc2[8];
        #pragma unroll
        for (int t = 0; t < 8; t++) { f32x4 z = {0.f, 0.f, 0.f, 0.f}; acc2[t] = z; }
        #pragma unroll
        for (int kb = 0; kb < 4; kb++) {
            half8 af = *(const half8*)(&myM1[s * 136 + kb * 32 + quad * 8]);
            #pragma unroll
            for (int t = 0; t < 8; t++) {
                half8 bf = *(const half8*)(&sW2[(((kb << 3) + t) * 64 + lane) * 8]);
                acc2[t] = __builtin_amdgcn_mfma_f32_16x16x32_f16(af, bf, acc2[t], 0, 0, 0);
            }
        }

        // epilogue 2: LN ; relu ; h += u
        #pragma unroll
        for (int r = 0; r < 4; r++) {
            int nn = nbase + quad * 4 + r;
            float v[8], sum = 0.f, sq = 0.f;
            #pragma unroll
            for (int t = 0; t < 8; t++) {
                v[t] = acc2[t][r] + b2c[t];
                sum += v[t]; sq += v[t] * v[t];
            }
            #pragma unroll
            for (int m = 1; m < 16; m <<= 1) {
                sum += __shfl_xor(sum, m, 64);
                sq  += __shfl_xor(sq, m, 64);
            }
            float mean = sum * (1.f / 128.f);
            float var = sq * (1.f / 128.f) - mean * mean;
            float rstd = rsqrtf(var + 1e-5f);
            if (nn < N_NODES) {
                float* hp = h + (size_t)nn * 128 + s * 8;
                float4 h0 = *(float4*)hp;
                float4 h1 = *(float4*)(hp + 4);
                float y[8];
                #pragma unroll
                for (int t = 0; t < 8; t++) {
                    float u = (v[t] - mean) * rstd * g2c[t] + be2c[t];
                    y[t] = fmaxf(u, 0.f);
                }
                h0.x += y[0]; h0.y += y[1]; h0.z += y[2]; h0.w += y[3];
                h1.x += y[4]; h1.y += y[5]; h1.z += y[6]; h1.w += y[7];
                *(float4*)hp = h0;
                *(float4*)(hp + 4) = h1;
            }
        }
    }
}

// ---------------- pool (parallel, segmented + atomics) ----------------
__global__ void pool_kernel(const float* __restrict__ h, const int* __restrict__ batch,
                            float* __restrict__ g) {
    const int CHUNK = 125;                       // 200 blocks x 125 nodes
    int blo = blockIdx.x * CHUNK;
    int bhi = blo + CHUNK; if (bhi > N_NODES) bhi = N_NODES;
    int j = threadIdx.x & 127;
    int half = threadIdx.x >> 7;                 // 2 nodes in flight per block
    float acc = 0.f; int cur = -1;
    for (int n = blo + half; n < bhi; n += 2) {
        int b = batch[n];
        if (b != cur) {
            if (cur >= 0) atomicAdd(&g[cur * 128 + j], acc);
            cur = b; acc = 0.f;
        }
        acc += h[(size_t)n * 128 + j];
    }
    if (cur >= 0) atomicAdd(&g[cur * 128 + j], acc);
}

// ---------------- pred ----------------
__global__ void pred_kernel(const float* __restrict__ g, const float* __restrict__ W1,
                            const float* __restrict__ b1, const float* __restrict__ W2,
                            const float* __restrict__ b2, float* __restrict__ out) {
    int b = blockIdx.x, j = threadIdx.x;
    float t = b1[j];
    for (int k = 0; k < 128; k++) t += g[b * 128 + k] * W1[k * 128 + j];
    t = fmaxf(t, 0.f);
    __shared__ float red[128];
    red[j] = t * W2[j];
    __syncthreads();
    for (int off = 64; off > 0; off >>= 1) {
        if (j < off) red[j] += red[j + off];
        __syncthreads();
    }
    if (j == 0) out[b] = red[0] + b2[0];
}

extern "C" void kernel_launch(void* const* d_in, const int* in_sizes, int n_in,
                              void* d_out, int out_size, void* d_ws, size_t ws_size,
                              hipStream_t stream) {
    const float* x      = (const float*)d_in[0];
    const float* pos    = (const float*)d_in[1];
    const int*   ei     = (const int*)d_in[2];
    const int*   batch  = (const int*)d_in[3];
    const float* emb_W  = (const float*)d_in[4];
    const float* emb_b  = (const float*)d_in[5];
    const float* msg_W1 = (const float*)d_in[6];
    const float* msg_b1 = (const float*)d_in[7];
    const float* msg_W2 = (const float*)d_in[8];
    const float* msg_b2 = (const float*)d_in[9];
    const float* upd_W1 = (const float*)d_in[10];
    const float* upd_b1 = (const float*)d_in[11];
    const float* upd_W2 = (const float*)d_in[12];
    const float* upd_b2 = (const float*)d_in[13];
    const float* msg_g1 = (const float*)d_in[14];
    const float* msg_be1= (const float*)d_in[15];
    const float* msg_g2 = (const float*)d_in[16];
    const float* msg_be2= (const float*)d_in[17];
    const float* upd_g1 = (const float*)d_in[18];
    const float* upd_be1= (const float*)d_in[19];
    const float* upd_g2 = (const float*)d_in[20];
    const float* upd_be2= (const float*)d_in[21];
    const float* pred_W1= (const float*)d_in[22];
    const float* pred_b1= (const float*)d_in[23];
    const float* pred_W2= (const float*)d_in[24];
    const float* pred_b2= (const float*)d_in[25];
    float* out = (float*)d_out;

    float* ws = (float*)d_ws;
    float*     h      = ws;                          // 3.2M floats
    _Float16*  U      = (_Float16*)(ws + 3200000);   // 3.2M f16
    _Float16*  S      = (_Float16*)(ws + 4800000);   // 3.2M f16
    _Float16*  m2     = (_Float16*)(ws + 6400000);   // 25.6M f16
    int*       cnt    = (int*)(ws + 19200000);
    int*       rowptr = cnt + 25008;
    int*       cursor = rowptr + 25008;
    int*       src_s  = cursor + 25008;
    int*       dst_s  = src_s + 200000;
    float*     dist_s = (float*)(dst_s + 200000);
    float*     g      = dist_s + 200000;

    hipMemsetAsync(cnt, 0, 25001 * sizeof(int), stream);
    hist_kernel<<<(N_EDGES + 255) / 256, 256, 0, stream>>>(ei, cnt);
    scan_kernel<<<1, 1024, 0, stream>>>(cnt, rowptr, cursor);
    scatter_kernel<<<(N_EDGES + 255) / 256, 256, 0, stream>>>(ei, pos, cursor, src_s, dst_s, dist_s);

    embed_kernel<<<4096, 256, 0, stream>>>(x, emb_W, emb_b, h);

    for (int l = 0; l < DEPTH; l++) {
        const float* W1l = msg_W1 + (size_t)l * 257 * 128;
        us_kernel<<<256, 512, 0, stream>>>(h, W1l, msg_b1 + l * 128, U, S);
        edge_kernel<<<512, 256, 0, stream>>>(
            U, S, dist_s, src_s, dst_s,
            W1l + 256 * 128, msg_g1 + l * 128, msg_be1 + l * 128,
            msg_W2 + (size_t)l * 128 * 128, msg_b2 + l * 128, msg_g2 + l * 128, msg_be2 + l * 128,
            m2);
        upd_kernel<<<256, 512, 0, stream>>>(
            h, m2, rowptr,
            upd_W1 + (size_t)l * 256 * 128, upd_b1 + l * 128, upd_g1 + l * 128, upd_be1 + l * 128,
            upd_W2 + (size_t)l * 128 * 128, upd_b2 + l * 128, upd_g2 + l * 128, upd_be2 + l * 128);
    }

    hipMemsetAsync(g, 0, N_GRAPHS * 128 * sizeof(float), stream);
    pool_kernel<<<200, 256, 0, stream>>>(h, batch, g);
    pred_kernel<<<64, 128, 0, stream>>>(g, pred_W1, pred_b1, pred_W2, pred_b2, out);
}